// Round 1
// 193.564 us; speedup vs baseline: 1.0276x; 1.0276x over previous
//
#include <hip/hip_runtime.h>

// ConfidenceCalibration: the reference's final reduction is
//   final = (calibrated[:,None] * softmax(logits)).sum(-1) = calibrated
// because softmax rows sum to 1 (verified absmax 0.0). The whole
// Linear->LN->GELU->Linear->softmax network multiplies the output by 1.
// Live path:
//   base  = sigmoid(mean(x, axis=-1))                    [B]
//   idx   = searchsorted(linspace(0,1,NB+1), base, 'right') - 1
//   scale = in_range(idx) ? bin_scaling[idx] : 0
//   out   = clip(base * scale, 0, 1)
// Memory-bound: one pass over x (128 MiB) -> ~21 us at 6.3 TB/s.
//
// R2 changes vs previous best (198.9 us):
//  - 2 rows per wave: 8 independent global_load_dwordx4 issued before any
//    dependent add -> 2x memory-level parallelism per wave, halves per-row
//    tail overhead (reductions for both rows interleaved so the 6-shfl
//    chains pipeline).
//  - nontemporal loads on x: single-use stream, skip cache allocate
//    (the harness's 512 MiB poison fill evicts x from L3 each iteration
//    anyway, so every timed run is a cold HBM stream).

typedef float f32x4 __attribute__((ext_vector_type(4)));

__device__ __forceinline__ void tail_row(const float* __restrict__ bin_scaling,
                                         float* __restrict__ out,
                                         size_t row, int NB, int D, float s) {
    const float m    = s / (float)D;
    const float base = 1.0f / (1.0f + expf(-m));

    // searchsorted(boundaries, base, 'right') - 1, boundaries = linspace(0,1,NB+1)
    int count = 0;
    for (int i = 0; i <= NB; ++i) {
        const float b = (float)i / (float)NB;
        count += (base >= b) ? 1 : 0;
    }
    const int idx = count - 1;

    const float scale = (idx >= 0 && idx < NB) ? bin_scaling[idx] : 0.0f;
    const float v0    = base * scale;
    out[row] = fminf(fmaxf(v0, 0.0f), 1.0f);
}

// D compile-time, R rows per wave. 256 threads = 4 waves, 4*R rows/block.
template <int D, int R>
__global__ __launch_bounds__(256) void ConfidenceCalibration_44985487458449_fast(
    const float* __restrict__ x,
    const float* __restrict__ bin_scaling,
    float* __restrict__ out,
    int B, int NB) {
    const int    wid  = (int)((blockIdx.x * blockDim.x + threadIdx.x) >> 6);
    const int    lane = threadIdx.x & 63;
    const size_t row0 = (size_t)wid * (size_t)R;
    if (row0 >= (size_t)B) return;

    constexpr int ITER = (D / 4) / 64;  // float4s per lane per row (4 for D=1024)

    if (row0 + R <= (size_t)B) {
        // Hot path: issue all R*ITER loads before any dependent arithmetic.
        f32x4 v[R][ITER];
        #pragma unroll
        for (int r = 0; r < R; ++r) {
            const f32x4* __restrict__ row =
                (const f32x4*)(x + (row0 + (size_t)r) * (size_t)D);
            #pragma unroll
            for (int i = 0; i < ITER; ++i)
                v[r][i] = __builtin_nontemporal_load(&row[lane + i * 64]);
        }

        float s[R];
        #pragma unroll
        for (int r = 0; r < R; ++r) {
            s[r] = 0.0f;
            #pragma unroll
            for (int i = 0; i < ITER; ++i)
                s[r] += (v[r][i].x + v[r][i].y) + (v[r][i].z + v[r][i].w);
        }

        // Interleaved 64-lane butterflies: R shuffle chains in flight.
        #pragma unroll
        for (int off = 32; off > 0; off >>= 1) {
            #pragma unroll
            for (int r = 0; r < R; ++r) s[r] += __shfl_down(s[r], off, 64);
        }

        if (lane == 0) {
            #pragma unroll
            for (int r = 0; r < R; ++r)
                tail_row(bin_scaling, out, row0 + (size_t)r, NB, D, s[r]);
        }
    } else {
        // Ragged tail (B not divisible by R): per-row fallback.
        for (int r = 0; r < R && row0 + (size_t)r < (size_t)B; ++r) {
            const f32x4* __restrict__ row =
                (const f32x4*)(x + (row0 + (size_t)r) * (size_t)D);
            float s = 0.0f;
            #pragma unroll
            for (int i = 0; i < ITER; ++i) {
                f32x4 t = __builtin_nontemporal_load(&row[lane + i * 64]);
                s += (t.x + t.y) + (t.z + t.w);
            }
            #pragma unroll
            for (int off = 32; off > 0; off >>= 1) s += __shfl_down(s, off, 64);
            if (lane == 0) tail_row(bin_scaling, out, row0 + (size_t)r, NB, D, s);
        }
    }
}

// Generic fallback (any D % 4 == 0), one wave per row.
__global__ __launch_bounds__(256) void ConfidenceCalibration_44985487458449_generic(
    const float* __restrict__ x,
    const float* __restrict__ bin_scaling,
    float* __restrict__ out,
    int B, int D, int NB) {
    const int gwave = (int)((blockIdx.x * blockDim.x + threadIdx.x) >> 6);
    const int lane  = threadIdx.x & 63;
    if (gwave >= B) return;

    const f32x4* __restrict__ row = (const f32x4*)(x + (size_t)gwave * (size_t)D);
    const int nvec = D >> 2;
    float s = 0.0f;
    for (int j = lane; j < nvec; j += 64) {
        f32x4 t = row[j];
        s += (t.x + t.y) + (t.z + t.w);
    }
    #pragma unroll
    for (int off = 32; off > 0; off >>= 1) s += __shfl_down(s, off, 64);
    if (lane == 0) tail_row(bin_scaling, out, (size_t)gwave, NB, D, s);
}

extern "C" void kernel_launch(void* const* d_in, const int* in_sizes, int n_in,
                              void* d_out, int out_size, void* d_ws, size_t ws_size,
                              hipStream_t stream) {
    // setup_inputs order: x, w1, b1, ln_g, ln_b, w2, b2, bin_scaling
    const float* x           = (const float*)d_in[0];
    const float* bin_scaling = (const float*)d_in[7];
    float* out = (float*)d_out;

    const int B  = out_size;              // 32768
    const int D  = in_sizes[0] / B;       // 1024
    const int NB = in_sizes[7];           // 15

    const int threads = 256;              // 4 waves per block

    if (D == 1024) {
        constexpr int R = 2;              // rows per wave
        const int rows_per_block = (threads / 64) * R;  // 8
        const int grid = (B + rows_per_block - 1) / rows_per_block;
        ConfidenceCalibration_44985487458449_fast<1024, R>
            <<<grid, threads, 0, stream>>>(x, bin_scaling, out, B, NB);
    } else {
        const int rows_per_block = threads / 64;
        const int grid = (B + rows_per_block - 1) / rows_per_block;
        ConfidenceCalibration_44985487458449_generic
            <<<grid, threads, 0, stream>>>(x, bin_scaling, out, B, D, NB);
    }
}

// Round 3
// 193.295 us; speedup vs baseline: 1.0290x; 1.0014x over previous
//
#include <hip/hip_runtime.h>

// ConfidenceCalibration: the reference's final reduction is
//   final = (calibrated[:,None] * softmax(logits)).sum(-1) = calibrated
// because softmax rows sum to 1 (verified absmax 0.0). The whole
// Linear->LN->GELU->Linear->softmax network multiplies the output by 1.
// Live path:
//   base  = sigmoid(mean(x, axis=-1))                    [B]
//   idx   = searchsorted(linspace(0,1,NB+1), base, 'right') - 1
//   scale = in_range(idx) ? bin_scaling[idx] : 0
//   out   = clip(base * scale, 0, 1)
// Memory-bound: one pass over x (128 MiB) -> ~21 us at 6.3 TB/s.
//
// R3 (resubmitted after GPU-acquisition timeout; never measured):
//  - R=4 rows per wave: 16 independent global_load_dwordx4 issued before
//    any dependent arithmetic (2x the in-flight bytes of R=2), quarters
//    per-row fixed cost. VGPR payload = 64; cap ~5 waves/SIMD, above the
//    4/SIMD the grid needs.
//  - xor-butterfly reduce (sum valid on ALL lanes) so lanes 0..R-1 each
//    run one row's tail (expf + searchsorted) in PARALLEL instead of
//    serialized on lane 0, and the R output stores are consecutive dwords.

typedef float f32x4 __attribute__((ext_vector_type(4)));

__device__ __forceinline__ float tail_val(const float* __restrict__ bin_scaling,
                                          int NB, int D, float s) {
    const float m    = s / (float)D;
    const float base = 1.0f / (1.0f + expf(-m));

    // searchsorted(boundaries, base, 'right') - 1, boundaries = linspace(0,1,NB+1)
    int count = 0;
    for (int i = 0; i <= NB; ++i) {
        const float b = (float)i / (float)NB;
        count += (base >= b) ? 1 : 0;
    }
    const int idx = count - 1;

    const float scale = (idx >= 0 && idx < NB) ? bin_scaling[idx] : 0.0f;
    const float v0    = base * scale;
    return fminf(fmaxf(v0, 0.0f), 1.0f);
}

// D compile-time, R rows per wave. 256 threads = 4 waves, 4*R rows/block.
template <int D, int R>
__global__ __launch_bounds__(256) void ConfidenceCalibration_44985487458449_fast(
    const float* __restrict__ x,
    const float* __restrict__ bin_scaling,
    float* __restrict__ out,
    int B, int NB) {
    const int    wid  = (int)((blockIdx.x * blockDim.x + threadIdx.x) >> 6);
    const int    lane = threadIdx.x & 63;
    const size_t row0 = (size_t)wid * (size_t)R;
    if (row0 >= (size_t)B) return;

    constexpr int ITER = (D / 4) / 64;  // float4s per lane per row (4 for D=1024)

    if (row0 + R <= (size_t)B) {
        // Hot path: issue all R*ITER loads before any dependent arithmetic.
        f32x4 v[R][ITER];
        #pragma unroll
        for (int r = 0; r < R; ++r) {
            const f32x4* __restrict__ row =
                (const f32x4*)(x + (row0 + (size_t)r) * (size_t)D);
            #pragma unroll
            for (int i = 0; i < ITER; ++i)
                v[r][i] = __builtin_nontemporal_load(&row[lane + i * 64]);
        }

        float s[R];
        #pragma unroll
        for (int r = 0; r < R; ++r) {
            s[r] = 0.0f;
            #pragma unroll
            for (int i = 0; i < ITER; ++i)
                s[r] += (v[r][i].x + v[r][i].y) + (v[r][i].z + v[r][i].w);
        }

        // Interleaved 64-lane XOR butterflies: R chains pipelined, and the
        // final sums are valid on EVERY lane (enables parallel tails below).
        #pragma unroll
        for (int off = 32; off > 0; off >>= 1) {
            #pragma unroll
            for (int r = 0; r < R; ++r) s[r] += __shfl_xor(s[r], off, 64);
        }

        // Lanes 0..R-1 each handle one row's tail in parallel; stores are
        // R consecutive dwords. Static selection (no runtime indexing ->
        // no scratch).
        if (lane < R) {
            float my = s[0];
            #pragma unroll
            for (int r = 1; r < R; ++r) my = (lane == r) ? s[r] : my;
            out[row0 + (size_t)lane] = tail_val(bin_scaling, NB, D, my);
        }
    } else {
        // Ragged tail (B not divisible by R): per-row fallback.
        for (int r = 0; r < R && row0 + (size_t)r < (size_t)B; ++r) {
            const f32x4* __restrict__ row =
                (const f32x4*)(x + (row0 + (size_t)r) * (size_t)D);
            float s = 0.0f;
            #pragma unroll
            for (int i = 0; i < ITER; ++i) {
                f32x4 t = __builtin_nontemporal_load(&row[lane + i * 64]);
                s += (t.x + t.y) + (t.z + t.w);
            }
            #pragma unroll
            for (int off = 32; off > 0; off >>= 1) s += __shfl_xor(s, off, 64);
            if (lane == 0) out[row0 + (size_t)r] = tail_val(bin_scaling, NB, D, s);
        }
    }
}

// Generic fallback (any D % 4 == 0), one wave per row.
__global__ __launch_bounds__(256) void ConfidenceCalibration_44985487458449_generic(
    const float* __restrict__ x,
    const float* __restrict__ bin_scaling,
    float* __restrict__ out,
    int B, int D, int NB) {
    const int gwave = (int)((blockIdx.x * blockDim.x + threadIdx.x) >> 6);
    const int lane  = threadIdx.x & 63;
    if (gwave >= B) return;

    const f32x4* __restrict__ row = (const f32x4*)(x + (size_t)gwave * (size_t)D);
    const int nvec = D >> 2;
    float s = 0.0f;
    for (int j = lane; j < nvec; j += 64) {
        f32x4 t = row[j];
        s += (t.x + t.y) + (t.z + t.w);
    }
    #pragma unroll
    for (int off = 32; off > 0; off >>= 1) s += __shfl_xor(s, off, 64);
    if (lane == 0) out[gwave] = tail_val(bin_scaling, NB, D, s);
}

extern "C" void kernel_launch(void* const* d_in, const int* in_sizes, int n_in,
                              void* d_out, int out_size, void* d_ws, size_t ws_size,
                              hipStream_t stream) {
    // setup_inputs order: x, w1, b1, ln_g, ln_b, w2, b2, bin_scaling
    const float* x           = (const float*)d_in[0];
    const float* bin_scaling = (const float*)d_in[7];
    float* out = (float*)d_out;

    const int B  = out_size;              // 32768
    const int D  = in_sizes[0] / B;       // 1024
    const int NB = in_sizes[7];           // 15

    const int threads = 256;              // 4 waves per block

    if (D == 1024) {
        constexpr int R = 4;              // rows per wave
        const int rows_per_block = (threads / 64) * R;  // 16
        const int grid = (B + rows_per_block - 1) / rows_per_block;
        ConfidenceCalibration_44985487458449_fast<1024, R>
            <<<grid, threads, 0, stream>>>(x, bin_scaling, out, B, NB);
    } else {
        const int rows_per_block = threads / 64;
        const int grid = (B + rows_per_block - 1) / rows_per_block;
        ConfidenceCalibration_44985487458449_generic
            <<<grid, threads, 0, stream>>>(x, bin_scaling, out, B, D, NB);
    }
}